// Round 2
// baseline (1843.640 us; speedup 1.0000x reference)
//
#include <hip/hip_runtime.h>

// out layout: (N_VERTICES, 2) row-major fp32: out[2*i] = cbar_i, out[2*i+1] = y_i.
//
// Strategy: per-XCD privatized accumulators in d_ws so fp32 scatter-atomics
// execute in the XCD-local L2 (workgroup-scope => no cross-XCD write-through),
// then a cheap 8-way reduce into d_out. Round-1 counters showed agent-scope
// atomics write through 32B/atomic to the coherence point (WRITE_SIZE ~1 GB).

#define GETREG_IMM(SZ, OFF, ID) ((((SZ)-1) << 11) | ((OFF) << 6) | (ID))
#define HW_REG_XCC_ID 20

constexpr int    kNumXcd     = 8;
constexpr size_t kCopyStride = 512 * 1024;  // floats => 2 MiB per copy, covers 500000

__global__ void edge_scatter_local(const int* __restrict__ eidx,
                                   const float* __restrict__ eattr,
                                   float* __restrict__ ws, int ne4) {
    // XCD id is uniform per workgroup; mask to [0,8) for safety.
    int xcc = __builtin_amdgcn_s_getreg(GETREG_IMM(32, 0, HW_REG_XCC_ID)) & (kNumXcd - 1);
    float* mycopy = ws + (size_t)xcc * kCopyStride;
    int tid = blockIdx.x * blockDim.x + threadIdx.x;
    int stride = gridDim.x * blockDim.x;
    for (int i = tid; i < ne4; i += stride) {
        int4   id = reinterpret_cast<const int4*>(eidx)[i];
        float4 v  = reinterpret_cast<const float4*>(eattr)[i];
        // Workgroup-scope relaxed: serviced at the local TCC (L2). Disjoint
        // copies per XCD keep this correct despite non-coherent L2s.
        __hip_atomic_fetch_add(&mycopy[id.x], v.x, __ATOMIC_RELAXED, __HIP_MEMORY_SCOPE_WORKGROUP);
        __hip_atomic_fetch_add(&mycopy[id.y], v.y, __ATOMIC_RELAXED, __HIP_MEMORY_SCOPE_WORKGROUP);
        __hip_atomic_fetch_add(&mycopy[id.z], v.z, __ATOMIC_RELAXED, __HIP_MEMORY_SCOPE_WORKGROUP);
        __hip_atomic_fetch_add(&mycopy[id.w], v.w, __ATOMIC_RELAXED, __HIP_MEMORY_SCOPE_WORKGROUP);
    }
}

__global__ void reduce_copies(const float* __restrict__ ws,
                              const float* __restrict__ vattr,
                              float* __restrict__ out, int n) {
    int i = blockIdx.x * blockDim.x + threadIdx.x;
    if (i < n) {
        float s = 0.0f;
        #pragma unroll
        for (int x = 0; x < kNumXcd; ++x) s += ws[(size_t)x * kCopyStride + i];
        float y = vattr[2 * i + 1];
        reinterpret_cast<float2*>(out)[i] = make_float2(s, y);
    }
}

// ---- Fallback path (ws too small): round-1 agent-scope version ----
__global__ void vertex_init_kernel(const float* __restrict__ vattr,
                                   float* __restrict__ out, int n) {
    int i = blockIdx.x * blockDim.x + threadIdx.x;
    if (i < n) {
        float2 va = reinterpret_cast<const float2*>(vattr)[i];
        reinterpret_cast<float2*>(out)[i] = make_float2(0.0f, va.y);
    }
}

__global__ void edge_scatter_agent(const int* __restrict__ eidx,
                                   const float* __restrict__ eattr,
                                   float* __restrict__ out, int ne4) {
    int tid = blockIdx.x * blockDim.x + threadIdx.x;
    int stride = gridDim.x * blockDim.x;
    for (int i = tid; i < ne4; i += stride) {
        int4   id = reinterpret_cast<const int4*>(eidx)[i];
        float4 v  = reinterpret_cast<const float4*>(eattr)[i];
        atomicAdd(&out[2 * id.x], v.x);
        atomicAdd(&out[2 * id.y], v.y);
        atomicAdd(&out[2 * id.z], v.z);
        atomicAdd(&out[2 * id.w], v.w);
    }
}

extern "C" void kernel_launch(void* const* d_in, const int* in_sizes, int n_in,
                              void* d_out, int out_size, void* d_ws, size_t ws_size,
                              hipStream_t stream) {
    const float* vattr = (const float*)d_in[0];   // (500000, 2) fp32
    const int*   eij   = (const int*)d_in[1];     // (2, 32000000) int32; row 0 = src idx
    const float* eattr = (const float*)d_in[2];   // (32000000, 1) fp32
    float* out = (float*)d_out;                   // (500000, 2) fp32

    const int n_vertices = in_sizes[0] / 2;
    const int n_edges    = in_sizes[2];
    const int ne4        = n_edges / 4;

    const size_t ws_needed = (size_t)kNumXcd * kCopyStride * sizeof(float);  // 16 MiB

    if (ws_size >= ws_needed) {
        float* ws = (float*)d_ws;
        // Zero the privatized copies (d_ws is poisoned 0xAA each call).
        hipMemsetAsync(d_ws, 0, ws_needed, stream);
        {
            int block = 256;
            int grid = 2048;
            edge_scatter_local<<<grid, block, 0, stream>>>(eij, eattr, ws, ne4);
        }
        {
            int block = 256;
            int grid = (n_vertices + block - 1) / block;
            reduce_copies<<<grid, block, 0, stream>>>(ws, vattr, out, n_vertices);
        }
    } else {
        // Fallback: agent-scope atomics directly into out.
        {
            int block = 256;
            int grid = (n_vertices + block - 1) / block;
            vertex_init_kernel<<<grid, block, 0, stream>>>(vattr, out, n_vertices);
        }
        {
            int block = 256;
            int grid = 2048;
            edge_scatter_agent<<<grid, block, 0, stream>>>(eij, eattr, out, ne4);
        }
    }
}